// Round 5
// baseline (176.145 us; speedup 1.0000x reference)
//
#include <hip/hip_runtime.h>
#include <hip/hip_bf16.h>

// Workspace layout (needs 34 MB):
//   [0, 2MB)    Ut : U^T as bf16, Ut[n][k] = bf16(U[k][n])
//   [2MB, 34MB) xg : gathered x as bf16, xg[b][i] = bf16(x[b][ans[b][i]])
#define WS_UT    ((size_t)0)
#define WS_XG    ((size_t)2*1024*1024)

typedef __attribute__((ext_vector_type(8))) short short8;
typedef __attribute__((ext_vector_type(4))) float floatx4;

__device__ __forceinline__ void load_lds16(const void* g, void* l) {
  __builtin_amdgcn_global_load_lds(
      (const __attribute__((address_space(1))) void*)g,
      (__attribute__((address_space(3))) void*)l, 16, 0, 0);
}

__device__ __forceinline__ unsigned short f2bf(float f) {
  __hip_bfloat16 h = __float2bfloat16(f);
  return __builtin_bit_cast(unsigned short, h);
}
__device__ __forceinline__ float bf2f(unsigned short u) {
  return __uint_as_float(((unsigned)u) << 16);
}

// ---------------- K1: prep (Ut = bf16(U^T)) + gather (xg) in one launch ----------------
// blocks [0,256): transpose+cast U.  blocks [256, 256+4096): per-row LDS gather of x.
__global__ void __launch_bounds__(256) prep_gather_k(const float* __restrict__ U,
                                                     const float* __restrict__ x,
                                                     const int* __restrict__ perm,
                                                     const int* __restrict__ prand,
                                                     unsigned short* __restrict__ ut,
                                                     unsigned short* __restrict__ xg) {
  __shared__ __align__(16) char smem[64 * 65 * 4];  // union: tile[64][65] f32 / xrow[4][1024] f32
  if (blockIdx.x < 256) {
    float (*tile)[65] = (float (*)[65])smem;
    const int tn = (blockIdx.x & 15) * 64;
    const int tk = (blockIdx.x >> 4) * 64;
    const int r = threadIdx.x >> 6;
    const int c = threadIdx.x & 63;
    for (int s = 0; s < 16; ++s)
      tile[s * 4 + r][c] = U[(size_t)(tk + s * 4 + r) * 1024 + tn + c];
    __syncthreads();
    for (int s = 0; s < 16; ++s)
      ut[(size_t)(tn + s * 4 + r) * 1024 + tk + c] = f2bf(tile[c][s * 4 + r]);
    return;
  }
  float (*xrow)[1024] = (float (*)[1024])smem;
  const int w = threadIdx.x >> 6, lane = threadIdx.x & 63;
  const int row = (blockIdx.x - 256) * 4 + w;
  const unsigned mult = ((unsigned)prand[0] * 6u) & 1023u;
  const unsigned br = (((unsigned)row & 1023u) * mult + 1u) & 1023u;
  const float* xr = x + (size_t)row * 1024;
  unsigned short* xo = xg + (size_t)row * 1024;
  for (int t = 0; t < 4; ++t) {
    floatx4 v = *(const floatx4*)(xr + t * 256 + lane * 4);
    *(floatx4*)(&xrow[w][t * 256 + lane * 4]) = v;
  }
  __syncthreads();
  for (int t = 0; t < 4; ++t) {
    int i0 = t * 256 + lane * 4;
    int4 p = *(const int4*)(perm + i0);
    ushort4 o;
    o.x = f2bf(xrow[w][((unsigned)p.x * br) & 1023u]);
    o.y = f2bf(xrow[w][((unsigned)p.y * br) & 1023u]);
    o.z = f2bf(xrow[w][((unsigned)p.z * br) & 1023u]);
    o.w = f2bf(xrow[w][((unsigned)p.w * br) & 1023u]);
    *(ushort4*)(xo + i0) = o;
  }
}

// ---------------- K2: fused GEMM + scatter + residual ----------------
// Tile M=64 x N=1024 (full row), grid 256 (1 block/CU), 512 threads (8 waves,
// wave w owns cols [w*128, w*128+128)).
// Round-5 change (pipeline fix; R4 was stage->drain->compute SERIAL:
// ~2430cy L2 B-delivery drain + ~2310cy LDS/MFMA per step, nothing
// overlapped -> MfmaUtil 19.5%):
//  * Half-K double buffer: BK=32 halves, {A:4KB, B:64KB} x2 = 136KB (same
//    footprint as R4's single 64-deep buffer).
//  * T3/T4 schedule per half-step h: issue stage(h+1) into other buffer ->
//    COUNTED s_waitcnt vmcnt(9|8) (own h loads retired; h+1's 9|8 loads stay
//    in flight ACROSS the barrier; never drain to 0 in-loop) -> s_barrier ->
//    12 ds_read_b128 + 32 MFMA -> s_barrier (protects buf h from stage(h+2),
//    no drain). L2 delivery of stage(h+1) overlaps compute(h).
//  * 64B-row swizzle: frag chunk = q ^ ((m>>1)&3) -> exactly 8 lanes per 16B
//    bank-slot (even = b128 minimum). Staging: linear LDS dest + inverse-
//    swizzled global source chunk = (lane&3) ^ ((lane>>3)&3).
__global__ void __launch_bounds__(512, 1) gemm_scatter_k(
    const unsigned short* __restrict__ xg,
    const unsigned short* __restrict__ ut,
    const int* __restrict__ perm,
    const int* __restrict__ prand,
    float* __restrict__ out) {
  extern __shared__ __align__(16) char smem[];
  // layout: Ah[2] = [0,8KB) (4KB each); Bh[2] = [8KB,136KB) (64KB each)
  const int tid = threadIdx.x;
  const int w = tid >> 6, lane = tid & 63;
  const int m = lane & 15, q = lane >> 4;
  const int R0 = blockIdx.x * 64;
  const int wn = w * 128;

  // fragment-read swizzle (64B rows, 4 chunks): chunk = q ^ ((m>>1)&3)
  const int cR = (q ^ ((m >> 1) & 3)) * 16;
  const int offA = m * 64 + cR;                 // + i*1024
  const int offB = w * 8192 + m * 64 + cR;      // + jj*1024

  // staging: each instr covers 16 rows x 4 slots; srow=lane>>2, slot=lane&3
  // LDS dest = base + lane*16 (linear); global chunk = slot ^ ((srow>>1)&3)
  const int srow = lane >> 2;
  const int schunk = ((lane & 3) ^ ((lane >> 3) & 3)) * 8;  // in shorts
  const unsigned short* bsrc = ut + (size_t)(w * 128 + srow) * 1024 + schunk;
  const unsigned short* asrc = xg + (size_t)(R0 + w * 16 + srow) * 1024 + schunk;  // w<4 only
  const int ldst = lane * 16;

  floatx4 acc[4][8];
#pragma unroll
  for (int i = 0; i < 4; ++i)
#pragma unroll
    for (int jj = 0; jj < 8; ++jj) acc[i][jj] = (floatx4)0.0f;

  // stage half h into buffer h&1 (9 loads for waves 0-3, 8 for waves 4-7)
  auto stage = [&](int h) {
    const int k0 = h * 32;  // shorts
    char* Ab = smem + (h & 1) * 4096;
    char* Bb = smem + 8192 + (h & 1) * 65536;
#pragma unroll
    for (int t = 0; t < 8; ++t)
      load_lds16(bsrc + (size_t)t * 16384 + k0, Bb + w * 8192 + t * 1024 + ldst);
    if (w < 4) load_lds16(asrc + k0, Ab + w * 1024 + ldst);
  };

  stage(0);
#pragma unroll
  for (int h = 0; h < 32; ++h) {
    if (h < 31) {
      stage(h + 1);
      if (w < 4) asm volatile("s_waitcnt vmcnt(9)" ::: "memory");
      else       asm volatile("s_waitcnt vmcnt(8)" ::: "memory");
    } else {
      asm volatile("s_waitcnt vmcnt(0)" ::: "memory");
    }
    __builtin_amdgcn_sched_barrier(0);
    __builtin_amdgcn_s_barrier();
    __builtin_amdgcn_sched_barrier(0);
    const char* Ab = smem + (h & 1) * 4096;
    const char* Bb = smem + 8192 + (h & 1) * 65536;
    short8 a[4], b[8];
#pragma unroll
    for (int i = 0; i < 4; ++i) a[i] = *(const short8*)(Ab + i * 1024 + offA);
#pragma unroll
    for (int jj = 0; jj < 8; ++jj) b[jj] = *(const short8*)(Bb + jj * 1024 + offB);
#pragma unroll
    for (int i = 0; i < 4; ++i)
#pragma unroll
      for (int jj = 0; jj < 8; ++jj)
        acc[i][jj] = __builtin_amdgcn_mfma_f32_16x16x32_bf16(b[jj], a[i],
                                                             acc[i][jj], 0, 0, 0);
    __builtin_amdgcn_sched_barrier(0);
    __builtin_amdgcn_s_barrier();
    __builtin_amdgcn_sched_barrier(0);
  }
  __syncthreads();  // all compute retired before sbuf overwrites buffers

  // ---- epilogue: 4 passes of 16 rows; value = s*y + xg scattered via LDS ----
  // FULLY UNROLLED: acc indices must be compile-time constants (rule #20).
  const unsigned mult = ((unsigned)prand[0] * 6u) & 1023u;
  const float rs = 0.33333334f;  // sqrt(0.1/0.9) = 1/3
  float* sbuf = (float*)smem;    // [16][1024] f32 (reuses A+B region)
#pragma unroll
  for (int i = 0; i < 4; ++i) {
    const int row = R0 + i * 16 + m;  // lane's y-row (swapped-mfma layout)
    const unsigned br = (((unsigned)row & 1023u) * mult + 1u) & 1023u;
    const unsigned short* xr = xg + (size_t)row * 1024;
#pragma unroll
    for (int jj = 0; jj < 8; ++jj) {
      const int j0 = wn + jj * 16 + q * 4;  // 4 consecutive y-cols per lane
      const int4 p4 = *(const int4*)(perm + j0);
      const ushort4 x4 = *(const ushort4*)(xr + j0);  // L2-hot (block's A panel)
      sbuf[m * 1024 + (((unsigned)p4.x * br) & 1023u)] = rs * acc[i][jj][0] + bf2f(x4.x);
      sbuf[m * 1024 + (((unsigned)p4.y * br) & 1023u)] = rs * acc[i][jj][1] + bf2f(x4.y);
      sbuf[m * 1024 + (((unsigned)p4.z * br) & 1023u)] = rs * acc[i][jj][2] + bf2f(x4.z);
      sbuf[m * 1024 + (((unsigned)p4.w * br) & 1023u)] = rs * acc[i][jj][3] + bf2f(x4.w);
    }
    __syncthreads();
    float* orow0 = out + (size_t)(R0 + i * 16) * 1024;
#pragma unroll
    for (int v = 0; v < 8; ++v) {
      const int f = v * 512 + tid;  // float4 index in [0,4096)
      *(floatx4*)(orow0 + ((f >> 8) * 1024 + (f & 255) * 4)) =
          *(const floatx4*)(sbuf + (size_t)f * 4);
    }
    if (i < 3) __syncthreads();
  }
}

extern "C" void kernel_launch(void* const* d_in, const int* in_sizes, int n_in,
                              void* d_out, int out_size, void* d_ws, size_t ws_size,
                              hipStream_t stream) {
  const float* x = (const float*)d_in[0];
  const float* U = (const float*)d_in[1];
  const int* perm = (const int*)d_in[2];
  const int* prand = (const int*)d_in[3];
  float* out = (float*)d_out;
  char* ws = (char*)d_ws;
  unsigned short* ut = (unsigned short*)(ws + WS_UT);
  unsigned short* xg = (unsigned short*)(ws + WS_XG);

  // 136KB dynamic LDS for K2 (above the 64KB default cap)
  hipFuncSetAttribute((const void*)gemm_scatter_k,
                      hipFuncAttributeMaxDynamicSharedMemorySize, 139264);

  prep_gather_k<<<256 + 4096, 256, 0, stream>>>(U, x, perm, prand, ut, xg);
  gemm_scatter_k<<<256, 512, 139264, stream>>>(xg, ut, perm, prand, out);
}